// Round 9
// baseline (227.724 us; speedup 1.0000x reference)
//
#include <hip/hip_runtime.h>
#include <hip/hip_bf16.h>

// Problem dims (fixed by reference setup_inputs)
#define M_DIM 32
#define K_DIM 8192
#define N_DIM 8192
#define KS 16                        // k-split slices
#define KCH (K_DIM / KS)             // 512 k per block
#define CHK 128                      // k per pipelined chunk
#define NCHK (KCH / CHK)             // 4 chunks
#define STEPS (CHK / 32)             // 4 MFMA k-steps per chunk
#define NPB 128                      // n-cols per block
#define MAIN_BLOCKS ((N_DIM / NPB) * KS)  // 1024

#define QW_ROWI4 (K_DIM / 8)         // 1024 int4 per qweight row
#define SC_ROW (K_DIM / 16)          // 512 f32 per scales row

// LDS strides (R6/R8-proven)
#define QROW 17                      // packed dwords per Q row (16 + 1)
#define AROW 136                     // f16 per A row (128 + 8)
#define SROW 9                       // f32 per S row (8 + 1)

typedef _Float16 half8   __attribute__((ext_vector_type(8)));
typedef _Float16 half4_t __attribute__((ext_vector_type(4)));
typedef float    floatx4 __attribute__((ext_vector_type(4)));

// ---- Proven E2M1 bit-decode (R1/R6/R8 pedigree, absmax 2.0) ----
__device__ __forceinline__ uint32_t dec2(uint32_t b) {
  uint32_t c0 = b & 0xFu, c1 = (b >> 4) & 0xFu;
  uint32_t m0 = c0 & 7u, m1 = c1 & 7u;
  uint32_t t0 = min(28u * m0, m0 + 28u);
  uint32_t t1 = min(28u * m1, m1 + 28u);
  return (t0 << 9) | ((c0 & 8u) << 12)
       | (t1 << 25) | ((c1 & 8u) << 28);
}

// Packed dword (4 payload bytes = 8 fp4 along k) -> 8 f16, times f16 scale.
__device__ __forceinline__ half8 decode8p(uint32_t q, _Float16 s) {
  union { uint32_t u[4]; half8 h; } w;
  w.u[0] = dec2(q & 0xFFu);
  w.u[1] = dec2((q >> 8) & 0xFFu);
  w.u[2] = dec2((q >> 16) & 0xFFu);
  w.u[3] = dec2((q >> 24) & 0xFFu);
  half8 sv = {s, s, s, s, s, s, s, s};
  return w.h * sv;
}

// inp f32 -> ws f16 (1 MB -> 512 KB, once)
__global__ void convertA_kernel(const floatx4* __restrict__ in4,
                                half4_t* __restrict__ out4) {
  int idx = blockIdx.x * blockDim.x + threadIdx.x;
  floatx4 f = in4[idx];
  half4_t h;
  h[0] = (_Float16)f[0]; h[1] = (_Float16)f[1];
  h[2] = (_Float16)f[2]; h[3] = (_Float16)f[3];
  out4[idx] = h;
}

// out = bias + sum of KS partial slabs
__global__ void reduce_kernel(const floatx4* __restrict__ part,
                              const floatx4* __restrict__ bias4,
                              floatx4* __restrict__ out4) {
  int idx = blockIdx.x * blockDim.x + threadIdx.x;   // [0, 65536)
  floatx4 acc = bias4[idx & (N_DIM / 4 - 1)];
#pragma unroll
  for (int s = 0; s < KS; ++s)
    acc += part[(size_t)s * (M_DIM * N_DIM / 4) + idx];
  out4[idx] = acc;
}

template <bool F16A>
__global__ __launch_bounds__(256, 4) void fp4_linear_kernel(
    const void*  __restrict__ Av,      // f16 [32][8192] (ws) or f32 (inp)
    const int4*  __restrict__ qw4,     // [N][1024] int4 view of [N, K/2] i32
    const float* __restrict__ scales,  // [8192, 512] f32
    const float* __restrict__ amaxp,   // [1]
    float*       __restrict__ part)    // [KS][32][8192] f32 partial slabs
{
  __shared__ uint32_t Qs[NPB * QROW];     // 8704 B (packed nibbles)
  __shared__ _Float16 As[M_DIM * AROW];   // 8704 B
  __shared__ float    Ss[NPB * SROW];     // 4608 B   -> 22016 B total

  const int t    = threadIdx.x;
  const int lane = t & 63;
  const int w    = t >> 6;

  // ---- XCD-locality swizzle (the R9 change) ----
  // Dispatch round-robins consecutive blockIdx across the 8 XCDs. Tie each
  // XCD to a contiguous 1/8 of N so its L2/fabric link pulls only ~19 MB
  // (its own n-rows), not the whole 150 MB working set. Its 128 blocks
  // (= all co-resident at 4 blk/CU x 32 CU) are 8 n-blocks x 16 k-slices,
  // each (n,k) tile loaded exactly once.
  const int xcd = blockIdx.x & 7;
  const int loc = blockIdx.x >> 3;        // [0, 128)
  const int nb  = xcd * 8 + (loc & 7);    // [0, 64)
  const int ks  = loc >> 3;               // [0, 16)
  const int n0  = nb * NPB;
  const int kb  = ks * KCH;
  const float amax = amaxp[0];

  // Per-thread staging geometry (fixed across chunks)
  const int qr = t >> 4, qc = t & 15;       // Q: 16 rows x 16 int4 per j-step
  const int4* qsrc = qw4 + (size_t)(n0 + qr) * QW_ROWI4 + ks * (KCH / 8) + qc;
  const int sr = t >> 1, sh = t & 1;        // S: 128 rows x 2 float4
  const float* ssrc = scales + (size_t)(n0 + sr) * SC_ROW + ks * (KCH / 16) + sh * 4;
  const int ar16 = t >> 4, ac16 = t & 15;
  const _Float16* asrc16 =
      (const _Float16*)Av + (size_t)ar16 * K_DIM + kb + ac16 * 8;
  const int ar32 = t >> 5, ac32 = t & 31;
  const float* asrc32 = (const float*)Av + (size_t)ar32 * K_DIM + kb + ac32 * 4;

  // Staging registers (const-indexed, fully unrolled -> no scratch; R8-proven)
  int4    qreg[8];
  half8   areg16[2];
  floatx4 areg32[4];
  floatx4 sreg;

  // ---------------- preload chunk 0 ----------------
  {
#pragma unroll
    for (int j = 0; j < 8; ++j)
      qreg[j] = qsrc[(size_t)j * 16 * QW_ROWI4];
    if (F16A) {
#pragma unroll
      for (int j = 0; j < 2; ++j)
        areg16[j] = *(const half8*)(asrc16 + (size_t)j * 16 * K_DIM);
    } else {
#pragma unroll
      for (int j = 0; j < 4; ++j)
        areg32[j] = *(const floatx4*)(asrc32 + (size_t)j * 8 * K_DIM);
    }
    sreg = *(const floatx4*)ssrc;
  }

  // Compute-side pointers
  const int row  = lane & 15;
  const int quad = lane >> 4;
  const int nloc = w * 32;
  const uint32_t* qAp = &Qs[(nloc + row) * QROW];
  const uint32_t* qBp = &Qs[(nloc + 16 + row) * QROW];
  const _Float16* a0p = &As[row * AROW];
  const _Float16* a1p = &As[(row + 16) * AROW];
  const float*    sAp = &Ss[(nloc + row) * SROW];
  const float*    sBp = &Ss[(nloc + 16 + row) * SROW];

  floatx4 acc00 = {0.f, 0.f, 0.f, 0.f};
  floatx4 acc01 = {0.f, 0.f, 0.f, 0.f};
  floatx4 acc10 = {0.f, 0.f, 0.f, 0.f};
  floatx4 acc11 = {0.f, 0.f, 0.f, 0.f};

  for (int c = 0; c < NCHK; ++c) {
    if (c) __syncthreads();              // previous chunk's LDS fully consumed

    // -------- store staged regs -> LDS --------
#pragma unroll
    for (int j = 0; j < 8; ++j) {
      uint32_t pk = ((uint32_t)qreg[j].x & 0xFFu)
                  | (((uint32_t)qreg[j].y & 0xFFu) << 8)
                  | (((uint32_t)qreg[j].z & 0xFFu) << 16)
                  | (((uint32_t)qreg[j].w & 0xFFu) << 24);
      Qs[(j * 16 + qr) * QROW + qc] = pk;
    }
    if (F16A) {
#pragma unroll
      for (int j = 0; j < 2; ++j)
        *(half8*)&As[(j * 16 + ar16) * AROW + ac16 * 8] = areg16[j];
    } else {
#pragma unroll
      for (int j = 0; j < 4; ++j) {
        floatx4 f = areg32[j];
        half4_t h;
        h[0] = (_Float16)f[0]; h[1] = (_Float16)f[1];
        h[2] = (_Float16)f[2]; h[3] = (_Float16)f[3];
        *(half4_t*)&As[(j * 8 + ar32) * AROW + ac32 * 4] = h;
      }
    }
    {
      float* sd = &Ss[sr * SROW + sh * 4];
      sd[0] = sreg[0] * amax; sd[1] = sreg[1] * amax;
      sd[2] = sreg[2] * amax; sd[3] = sreg[3] * amax;
    }
    __syncthreads();

    // -------- issue next chunk's loads (in flight during compute) --------
    if (c + 1 < NCHK) {
      const int co = c + 1;
#pragma unroll
      for (int j = 0; j < 8; ++j)
        qreg[j] = qsrc[(size_t)j * 16 * QW_ROWI4 + co * (CHK / 8)];
      if (F16A) {
#pragma unroll
        for (int j = 0; j < 2; ++j)
          areg16[j] = *(const half8*)(asrc16 + (size_t)j * 16 * K_DIM + co * CHK);
      } else {
#pragma unroll
        for (int j = 0; j < 4; ++j)
          areg32[j] = *(const floatx4*)(asrc32 + (size_t)j * 8 * K_DIM + co * CHK);
      }
      sreg = *(const floatx4*)(ssrc + co * (CHK / 16));
    }

    // -------- compute chunk c from LDS --------
#pragma unroll
    for (int it = 0; it < STEPS; ++it) {
      const uint32_t qA = qAp[it * 4 + quad];
      const uint32_t qB = qBp[it * 4 + quad];
      const _Float16 sA = (_Float16)sAp[it * 2 + (quad >> 1)];
      const _Float16 sB = (_Float16)sBp[it * 2 + (quad >> 1)];
      half8 bA = decode8p(qA, sA);
      half8 bB = decode8p(qB, sB);
      half8 a0 = *(const half8*)(a0p + it * 32 + quad * 8);
      half8 a1 = *(const half8*)(a1p + it * 32 + quad * 8);
      acc00 = __builtin_amdgcn_mfma_f32_16x16x32_f16(a0, bA, acc00, 0, 0, 0);
      acc01 = __builtin_amdgcn_mfma_f32_16x16x32_f16(a0, bB, acc01, 0, 0, 0);
      acc10 = __builtin_amdgcn_mfma_f32_16x16x32_f16(a1, bA, acc10, 0, 0, 0);
      acc11 = __builtin_amdgcn_mfma_f32_16x16x32_f16(a1, bB, acc11, 0, 0, 0);
    }
  }

  // ---- Epilogue: partial slab store. D: col(n)=lane&15, row(m)=quad*4+reg. ----
  float* pb = part + (size_t)ks * (M_DIM * N_DIM);
#pragma unroll
  for (int r = 0; r < 4; ++r) {
    const int m = quad * 4 + r;
    float* o0 = pb + (size_t)m * N_DIM + n0 + nloc;
    float* o1 = pb + (size_t)(m + 16) * N_DIM + n0 + nloc;
    o0[row]      = acc00[r];
    o0[16 + row] = acc01[r];
    o1[row]      = acc10[r];
    o1[16 + row] = acc11[r];
  }
}

extern "C" void kernel_launch(void* const* d_in, const int* in_sizes, int n_in,
                              void* d_out, int out_size, void* d_ws, size_t ws_size,
                              hipStream_t stream) {
  const float* inp    = (const float*)d_in[0];
  const int4*  qw4    = (const int4*)d_in[1];
  const float* scales = (const float*)d_in[2];
  const float* amaxp  = (const float*)d_in[3];
  const float* bias   = (const float*)d_in[4];
  float* out = (float*)d_out;

  const size_t part_bytes = (size_t)KS * M_DIM * N_DIM * sizeof(float);  // 16.8 MB
  const size_t a16_bytes  = (size_t)M_DIM * K_DIM * sizeof(_Float16);    // 512 KB
  float* partp = (float*)d_ws;                       // partials first

  if (ws_size >= part_bytes + a16_bytes) {
    _Float16* Af16 = (_Float16*)((char*)d_ws + part_bytes);
    convertA_kernel<<<M_DIM * K_DIM / 4 / 256, 256, 0, stream>>>(
        (const floatx4*)inp, (half4_t*)Af16);
    fp4_linear_kernel<true><<<MAIN_BLOCKS, 256, 0, stream>>>(
        Af16, qw4, scales, amaxp, partp);
  } else {
    fp4_linear_kernel<false><<<MAIN_BLOCKS, 256, 0, stream>>>(
        inp, qw4, scales, amaxp, partp);
  }
  reduce_kernel<<<M_DIM * N_DIM / 4 / 256, 256, 0, stream>>>(
      (const floatx4*)partp, (const floatx4*)bias, (floatx4*)out);
}